// Round 15
// baseline (266.703 us; speedup 1.0000x reference)
//
#include <hip/hip_runtime.h>

namespace {
constexpr int kB = 2;
constexpr int kC = 256;
constexpr int kH = 56;
constexpr int kW = 56;
constexpr int kN = kH * kW;        // 3136
constexpr int kNH = 8;
constexpr int kHD = 32;
constexpr int kNF = kW / 2 + 1;    // 29
constexpr int kSpec = kH * kNF;    // 1624
constexpr long kCN = (long)kC * kN;        // 802816
constexpr float kAttScale = 0.17677669529663687f;   // 32^-0.5
constexpr float kLog2e = 1.4426950408889634f;
constexpr float kAng = 6.283185307179586f / 56.0f;  // 2*pi/56
// twiddle table offsets in u16 units
constexpr int TW1F = 0;            // [128][64]
constexpr int TW2F = 8192;         // [64][64]
constexpr int TW1I = 12288;        // [128][64]
constexpr int TW2I = 20480;        // [64][64]
constexpr int TWTOT = 24576;
}

typedef __attribute__((ext_vector_type(8))) short short8;
typedef __attribute__((ext_vector_type(4))) float float4v;

union Frag {
    short8 s;
    unsigned short u[8];
    uint2 u2[2];
    uint4 u4;
};

__device__ __forceinline__ unsigned short f2b(float f) {
    unsigned u = __float_as_uint(f);
    return (unsigned short)((u + 0x7FFFu + ((u >> 16) & 1u)) >> 16);
}
__device__ __forceinline__ float b2f(unsigned short u) {
    return __uint_as_float((unsigned)u << 16);
}
__device__ __forceinline__ unsigned f2b_pk(float a, float b) {
    unsigned ua = __float_as_uint(a); ua = (ua + 0x7FFFu + ((ua >> 16) & 1u)) >> 16;
    unsigned ub = __float_as_uint(b); ub = (ub + 0x7FFFu + ((ub >> 16) & 1u)) >> 16;
    return ua | (ub << 16);
}
__device__ __forceinline__ unsigned pk_trunc(float a, float b) {
    return (__float_as_uint(a) >> 16) | (__float_as_uint(b) & 0xFFFF0000u);
}
__device__ __forceinline__ uint4 pk8(const float* v) {
    return make_uint4(f2b_pk(v[0], v[1]), f2b_pk(v[2], v[3]),
                      f2b_pk(v[4], v[5]), f2b_pk(v[6], v[7]));
}

// ---------------------------------------------------------------------------
// Twiddle body (bf16 tables into d_ws)
// ---------------------------------------------------------------------------
__device__ void twiddle_body(int blk, unsigned short* __restrict__ tw)
{
    int idx = blk * 256 + threadIdx.x;
    if (idx >= TWTOT) return;
    float val = 0.f;
    if (idx < TW2F) {                       // TW1F
        int r = idx >> 6, c = idx & 63;
        if (c < 56) {
            if (r < 56)       val = cosf(kAng * (float)((r * c) % 56));
            else if (r < 112) val = sinf(kAng * (float)(((r - 56) * c) % 56));
        }
    } else if (idx < TW1I) {                // TW2F
        int t = idx - TW2F; int r = t >> 6, c = t & 63;
        if (c < 56) {
            if (r < 29)                  val = cosf(kAng * (float)((r * c) % 56));
            else if (r >= 32 && r < 61)  val = sinf(kAng * (float)(((r - 32) * c) % 56));
        }
    } else if (idx < TW2I) {                // TW1I
        int t = idx - TW1I; int r = t >> 6, c = t & 63;
        if (c < 56) {
            if (r < 56)                  val = cosf(kAng * (float)((r * c) % 56));
            else if (r >= 64 && r < 120) val = sinf(kAng * (float)(((r - 64) * c) % 56));
        }
    } else {                                // TW2I
        int t = idx - TW2I; int x = t >> 6, c = t & 63;
        if (x < 56 && c < 58) {
            int v = c >> 1;
            float wv = ((v == 0) || (v == 28)) ? 1.f : 2.f;
            float a = kAng * (float)((v * x) % 56);
            val = (c & 1) ? (-wv * sinf(a)) : (wv * cosf(a));
        }
    }
    tw[idx] = f2b(val);
}

// ---------------------------------------------------------------------------
// GEMM body (bias epilogue). Weight/bias rows: o0; output rows: oY.
// smem: Wt[64][40] @0 (5120 B) + Xt[128][40] @5120 (10240 B) = 15360 B
// ---------------------------------------------------------------------------
__device__ void gemm_bias_body(char* smem, const float* __restrict__ Wm,
                               const float* __restrict__ Xb,
                               const float* __restrict__ bias, float* __restrict__ Yb,
                               int o0, int oY, int n0, int CI)
{
    unsigned short (*Wt)[40] = (unsigned short(*)[40])smem;
    unsigned short (*Xt)[40] = (unsigned short(*)[40])(smem + 5120);

    const int tid = threadIdx.x;
    const int wave = tid >> 6, lane = tid & 63;
    const int ln = lane & 15, qd = lane >> 4;
    const int wy = wave >> 1, wx = wave & 1;

    const int ow = tid >> 2, kcw = tid & 3;
    const int nx = tid & 127, kcx = tid >> 7;
    const bool xvalid = (n0 + nx) < kN;

    float4v acc[2][4];
#pragma unroll
    for (int i = 0; i < 2; ++i)
#pragma unroll
        for (int j = 0; j < 4; ++j) acc[i][j] = (float4v){0.f, 0.f, 0.f, 0.f};

    float wpre[8], xpre[16];
    {
        const float* ws = Wm + (long)(o0 + ow) * CI + kcw * 8;
        *(float4*)&wpre[0] = *(const float4*)ws;
        *(float4*)&wpre[4] = *(const float4*)(ws + 4);
#pragma unroll
        for (int j = 0; j < 16; ++j)
            xpre[j] = xvalid ? Xb[(long)(kcx * 16 + j) * kN + n0 + nx] : 0.f;
    }

    for (int k0 = 0; k0 < CI; k0 += 32) {
        *(uint4*)&Wt[ow][kcw * 8]      = pk8(wpre);
        *(uint4*)&Xt[nx][kcx * 16]     = pk8(xpre);
        *(uint4*)&Xt[nx][kcx * 16 + 8] = pk8(xpre + 8);
        __syncthreads();

        if (k0 + 32 < CI) {
            const float* ws = Wm + (long)(o0 + ow) * CI + k0 + 32 + kcw * 8;
            *(float4*)&wpre[0] = *(const float4*)ws;
            *(float4*)&wpre[4] = *(const float4*)(ws + 4);
#pragma unroll
            for (int j = 0; j < 16; ++j)
                xpre[j] = xvalid ? Xb[(long)(k0 + 32 + kcx * 16 + j) * kN + n0 + nx] : 0.f;
        }

        Frag af[2], bf4[4];
#pragma unroll
        for (int mt = 0; mt < 2; ++mt)
            af[mt].u4 = *(const uint4*)&Wt[wy * 32 + mt * 16 + ln][qd * 8];
#pragma unroll
        for (int nt = 0; nt < 4; ++nt)
            bf4[nt].u4 = *(const uint4*)&Xt[wx * 64 + nt * 16 + ln][qd * 8];
#pragma unroll
        for (int mt = 0; mt < 2; ++mt)
#pragma unroll
            for (int nt = 0; nt < 4; ++nt)
                acc[mt][nt] = __builtin_amdgcn_mfma_f32_16x16x32_bf16(
                    af[mt].s, bf4[nt].s, acc[mt][nt], 0, 0, 0);
        __syncthreads();
    }

#pragma unroll
    for (int mt = 0; mt < 2; ++mt) {
        const int obL = o0 + wy * 32 + mt * 16 + qd * 4;
        const int obY = oY + wy * 32 + mt * 16 + qd * 4;
#pragma unroll
        for (int nt = 0; nt < 4; ++nt) {
            const int n = n0 + wx * 64 + nt * 16 + ln;
            if (n < kN) {
#pragma unroll
                for (int r = 0; r < 4; ++r) {
                    float v = acc[mt][nt][r];
                    if (bias) v += bias[obL + r];
                    Yb[(long)(obY + r) * kN + n] = v;
                }
            }
        }
    }
}

// ---------------------------------------------------------------------------
// Mega dispatch 1: twiddle init + all 4 projection GEMMs (1296 blocks).
// [0,96): twiddle; [96,496): q-projections; [496,1296): kv-projections.
// ---------------------------------------------------------------------------
__global__ __launch_bounds__(256)
void init_proj_kernel(unsigned short* __restrict__ tw,
                      const float* __restrict__ x, const float* __restrict__ ctx,
                      const float* __restrict__ s_q_w, const float* __restrict__ t_q_w,
                      const float* __restrict__ s_kv_w, const float* __restrict__ t_kv_w,
                      float* __restrict__ sq, float* __restrict__ tq,
                      float* __restrict__ skv, float* __restrict__ tkv)
{
    __shared__ __align__(16) char smem[15360];
    int bi = blockIdx.x;
    if (bi < 96) { twiddle_body(bi, tw); return; }
    bi -= 96;
    if (bi < 400) {
        // q-projections: 2b x 8y x 25n
        int b = bi / 200, rem = bi % 200;
        int y = rem / 25, xb = rem % 25;
        int sel = y >= 4;
        int o0 = (sel ? y - 4 : y) * 64;
        gemm_bias_body(smem, sel ? t_q_w : s_q_w, (x + (long)b * kCN), nullptr,
                       (sel ? tq : sq) + (long)b * kCN, o0, o0, xb * 128, kC);
    } else {
        bi -= 400;
        int b = bi / 400, rem = bi % 400;
        int y = rem / 25, xb = rem % 25;
        int sel = y >= 8;
        int o0 = (sel ? y - 8 : y) * 64;
        gemm_bias_body(smem, sel ? t_kv_w : s_kv_w, (ctx + (long)b * kCN), nullptr,
                       (sel ? tkv : skv) + (long)b * 2 * kCN, o0, o0, xb * 128, kC);
    }
}

// ---------------------------------------------------------------------------
// Forward 2D DFT body — TRANSPOSE-FREE (round 15).
// Phase 1: H[y][vc] = sum_x img[y][x]*TW2F[vc][x]   (A=img row-major, no scatter)
// Phase 2: D2[uc][vc] = sum_y TW1F[uc][y]*H[y][vc]
// Qr = D2[u][v] - D2[56+u][32+v]; Qi = -D2[56+u][v] - D2[u][32+v]
// LDS: HT[64 vc][72] @0 (9216) | imgR[64 y][72] @9216 (9216, dead after ph.1)
//      YT[64 vc][136 uc] @9216 (17408, overlays imgR). Total 26624 B.
// ---------------------------------------------------------------------------
__device__ void dft_fwd_body(char* smem, int bx,
                             const float* __restrict__ s0, const float* __restrict__ s1,
                             const float* __restrict__ s2, float* __restrict__ d0,
                             float* __restrict__ d1, float* __restrict__ d2,
                             const unsigned short* __restrict__ tw)
{
    const int which = bx >> 9, ch = bx & 511;
    const int b = ch >> 8, c = ch & 255;
    const float* src; long stride; float* spec;
    if (which == 0)      { src = s0; stride = kCN;     spec = d0; }
    else if (which == 1) { src = s1; stride = 2 * kCN; spec = d1; }
    else                 { src = s2; stride = 2 * kCN; spec = d2; }
    const float* img = src + (long)b * stride + (long)c * kN;

    unsigned short (*HT)[72]   = (unsigned short(*)[72])smem;            // 9216
    unsigned short (*imgR)[72] = (unsigned short(*)[72])(smem + 9216);   // 9216
    unsigned short (*YT)[136]  = (unsigned short(*)[136])(smem + 9216);  // 17408 overlay

    const int tid = threadIdx.x;
    const int wave = tid >> 6, lane = tid & 63;
    const int ln = lane & 15, qd = lane >> 4;

    // zero pads (rows >=56 fully; cols 56..71) — NaN guard for MFMA
    for (int i = tid; i < 64 * 72; i += 256) {
        int r = i / 72, cc = i - r * 72;
        if (r >= 56 || cc >= 56) imgR[r][cc] = 0;
    }
    // fill row-major, vectorized: 784 chunks of 4 (56 % 4 == 0, no row cross)
    for (int e = tid; e < 784; e += 256) {
        int y = e / 14, x0 = (e % 14) * 4;
        float4 v4 = *(const float4*)(img + y * 56 + x0);
        *(uint2*)&imgR[y][x0] = make_uint2(f2b_pk(v4.x, v4.y), f2b_pk(v4.z, v4.w));
    }
    __syncthreads();

    // phase 1: wave w -> y-tile w (m=y); 4 n-tiles over vc
    float4v acc1[4];
#pragma unroll
    for (int n = 0; n < 4; ++n) acc1[n] = (float4v){0.f, 0.f, 0.f, 0.f};
#pragma unroll
    for (int ks = 0; ks < 2; ++ks) {
        Frag a;
        a.u4 = *(const uint4*)&imgR[wave * 16 + ln][ks * 32 + qd * 8];
#pragma unroll
        for (int nt = 0; nt < 4; ++nt) {
            Frag bb;
            bb.u4 = *(const uint4*)(tw + TW2F + (nt * 16 + ln) * 64 + ks * 32 + qd * 8);
            acc1[nt] = __builtin_amdgcn_mfma_f32_16x16x32_bf16(a.s, bb.s, acc1[nt], 0, 0, 0);
        }
    }
    // D[m=y][n=vc] -> HT[vc][y], b64 writes (y = wave*16 + qd*4 + r)
#pragma unroll
    for (int nt = 0; nt < 4; ++nt)
        *(uint2*)&HT[nt * 16 + ln][wave * 16 + qd * 4] =
            make_uint2(f2b_pk(acc1[nt][0], acc1[nt][1]),
                       f2b_pk(acc1[nt][2], acc1[nt][3]));
    __syncthreads();

    // phase 2: wave w -> uc-tiles 2w, 2w+1; 4 n-tiles over vc
    float4v acc2[2][4];
#pragma unroll
    for (int m = 0; m < 2; ++m)
#pragma unroll
        for (int n = 0; n < 4; ++n) acc2[m][n] = (float4v){0.f, 0.f, 0.f, 0.f};
#pragma unroll
    for (int ks = 0; ks < 2; ++ks) {
        Frag a[2], bb[4];
#pragma unroll
        for (int mt = 0; mt < 2; ++mt)
            a[mt].u4 = *(const uint4*)(tw + TW1F + ((2 * wave + mt) * 16 + ln) * 64 + ks * 32 + qd * 8);
#pragma unroll
        for (int nt = 0; nt < 4; ++nt)
            bb[nt].u4 = *(const uint4*)&HT[nt * 16 + ln][ks * 32 + qd * 8];
#pragma unroll
        for (int mt = 0; mt < 2; ++mt)
#pragma unroll
            for (int nt = 0; nt < 4; ++nt)
                acc2[mt][nt] = __builtin_amdgcn_mfma_f32_16x16x32_bf16(a[mt].s, bb[nt].s, acc2[mt][nt], 0, 0, 0);
    }
    // D2[m=uc][n=vc] -> YT[vc][uc], b64 writes (uc = (2w+mt)*16 + qd*4 + r)
#pragma unroll
    for (int mt = 0; mt < 2; ++mt)
#pragma unroll
        for (int nt = 0; nt < 4; ++nt)
            *(uint2*)&YT[nt * 16 + ln][(2 * wave + mt) * 16 + qd * 4] =
                make_uint2(f2b_pk(acc2[mt][nt][0], acc2[mt][nt][1]),
                           f2b_pk(acc2[mt][nt][2], acc2[mt][nt][3]));
    __syncthreads();

    float2* outp = (float2*)spec + (long)ch * kSpec;
    for (int i = tid; i < kSpec; i += 256) {
        int u = i / kNF, v = i - u * kNF;
        float Qr = b2f(YT[v][u]) - b2f(YT[32 + v][56 + u]);
        float Qi = -b2f(YT[v][56 + u]) - b2f(YT[32 + v][u]);
        outp[i] = make_float2(Qr, Qi);
    }
}

// ---------------------------------------------------------------------------
// Attention K/V prepack body
// ---------------------------------------------------------------------------
__device__ void prepack_body(char* smem, int blk, const float* __restrict__ tkv,
                             unsigned short* __restrict__ Kp,
                             unsigned short* __restrict__ Vp)
{
    const int i = blk % 49;
    const int h = (blk / 49) & 7;
    const int b = blk / (49 * 8);
    const float* kb = tkv + (long)b * 2 * kCN + (long)h * kHD * kN;
    const float* vb = kb + kCN;
    const int tid = threadIdx.x;

    float (*Ks)[72] = (float(*)[72])smem;
#pragma unroll
    for (int j = 0; j < 8; ++j) {
        int e = tid + j * 256;
        int d = e >> 6, c = e & 63;
        Ks[d][c] = kb[(long)d * kN + i * 64 + c];
    }
    __syncthreads();
    {
        int tl = tid >> 6, lnn = (tid >> 2) & 15, qdd = tid & 3;
        float v[8];
#pragma unroll
        for (int j = 0; j < 8; ++j) v[j] = Ks[qdd * 8 + j][tl * 16 + lnn];
        unsigned short* dst = Kp + ((long)(b * 8 + h) * 196 + 4 * i + tl) * 512 + lnn * 32 + qdd * 8;
        *(uint4*)dst = pk8(v);
    }
    {
        int g = tid >> 7, dh = (tid >> 6) & 1, lnn = (tid >> 2) & 15, qdd = tid & 3;
        int d = dh * 16 + lnn;
        const float* src = vb + (long)d * kN + i * 64 + g * 32 + qdd * 8;
        float v[8];
        *(float4*)&v[0] = *(const float4*)src;
        *(float4*)&v[4] = *(const float4*)(src + 4);
        unsigned short* dst = Vp + ((long)(b * 8 + h) * 49 + i) * 2048 + ((g * 2 + dh) * 16 + lnn) * 32 + qdd * 8;
        *(uint4*)dst = pk8(v);
    }
}

// ---------------------------------------------------------------------------
// Mega dispatch 2: [0,1536) forward DFTs; [1536,2320) K/V prepack.
// ---------------------------------------------------------------------------
__global__ __launch_bounds__(256)
void fwd3_prepack_kernel(const float* __restrict__ s0, const float* __restrict__ s1,
                         const float* __restrict__ s2, float* __restrict__ d0,
                         float* __restrict__ d1, float* __restrict__ d2,
                         const unsigned short* __restrict__ tw,
                         const float* __restrict__ tkv,
                         unsigned short* __restrict__ Kp, unsigned short* __restrict__ Vp)
{
    __shared__ __align__(16) char smem[26624];
    if (blockIdx.x < 1536)
        dft_fwd_body(smem, blockIdx.x, s0, s1, s2, d0, d1, d2, tw);
    else
        prepack_body(smem, blockIdx.x - 1536, tkv, Kp, Vp);
}

// ---------------------------------------------------------------------------
// Inverse 2D DFT body (bf16 Yb; smem 27648 B)
// ---------------------------------------------------------------------------
__device__ void dft_inv_body(char* smem, int bx,
                             const float* __restrict__ fQ, const float* __restrict__ fK,
                             const float* __restrict__ fV, const float* __restrict__ cw,
                             float* __restrict__ dst1, float* __restrict__ dst2,
                             const float* __restrict__ skvp, const float* __restrict__ dww,
                             const float* __restrict__ dwb, const unsigned short* __restrict__ tw)
{
    const int unit = bx >> 9;
    const int ch = bx & 511;
    const int b = ch >> 8, c = ch & 255;
    unsigned short (*Pb)[72]  = (unsigned short(*)[72])smem;           // 9216
    unsigned short (*Yb)[72]  = (unsigned short(*)[72])(smem + 9216);  // 18432
    unsigned short (*T2)[72]  = (unsigned short(*)[72])smem;           // overlays Pb
    float (*svs)[65]          = (float(*)[65])(smem + 9216);           // overlays Yb

    const int tid = threadIdx.x;
    const int wave = tid >> 6, lane = tid & 63;
    const int ln = lane & 15, qd = lane >> 4;

    const float2* Pin; const float2* Min; float scale; float* dst;
    if (unit == 0) {
        Pin = (const float2*)fQ + (long)ch * kSpec;
        Min = (const float2*)fK + (long)ch * kSpec;
        scale = 1.0f / 175616.0f; dst = dst1;
    } else {
        Pin = (const float2*)fV + (long)ch * kSpec;
        Min = (const float2*)cw + (long)c * kSpec;
        scale = 1.0f / 3136.0f; dst = dst2;
    }

    for (int i = tid; i < 64 * 72; i += 256) {
        int r = i / 72, cc = i - r * 72;
        if (r >= 58 || cc >= 56) Pb[r][cc] = 0;
    }
    for (int i = tid; i < kSpec; i += 256) {
        int u = i / kNF, v = i - u * kNF;
        float2 p = Pin[i];
        float2 m = Min[i];
        float pr = (p.x * m.x - p.y * m.y) * scale;
        float pi = (p.x * m.y + p.y * m.x) * scale;
        Pb[2 * v][u]     = f2b(pr);
        Pb[2 * v + 1][u] = f2b(pi);
    }
    __syncthreads();

    float4v acc1[2][4];
#pragma unroll
    for (int m = 0; m < 2; ++m)
#pragma unroll
        for (int n = 0; n < 4; ++n) acc1[m][n] = (float4v){0.f, 0.f, 0.f, 0.f};
#pragma unroll
    for (int ks = 0; ks < 2; ++ks) {
        Frag a[2], bf[4];
#pragma unroll
        for (int m = 0; m < 2; ++m)
            a[m].u4 = *(const uint4*)(tw + TW1I + ((2 * wave + m) * 16 + ln) * 64 + ks * 32 + qd * 8);
#pragma unroll
        for (int n = 0; n < 4; ++n)
            bf[n].u4 = *(const uint4*)&Pb[n * 16 + ln][ks * 32 + qd * 8];
#pragma unroll
        for (int m = 0; m < 2; ++m)
#pragma unroll
            for (int n = 0; n < 4; ++n)
                acc1[m][n] = __builtin_amdgcn_mfma_f32_16x16x32_bf16(a[m].s, bf[n].s, acc1[m][n], 0, 0, 0);
    }
#pragma unroll
    for (int m = 0; m < 2; ++m)
#pragma unroll
        for (int n = 0; n < 4; ++n)
#pragma unroll
            for (int r = 0; r < 4; ++r)
                Yb[(2 * wave + m) * 16 + qd * 4 + r][n * 16 + ln] = f2b(acc1[m][n][r]);
    __syncthreads();

    for (int i = tid; i < 64 * 72; i += 256) {
        int r = i / 72, cc = i - r * 72;
        if (r >= 56 || cc >= 58) T2[r][cc] = 0;
    }
    __syncthreads();
    for (int i = tid; i < 56 * kNF; i += 256) {
        int y = i / kNF, v = i - y * kNF;
        float Tr = b2f(Yb[y][2 * v])     - b2f(Yb[64 + y][2 * v + 1]);
        float Ti = b2f(Yb[y][2 * v + 1]) + b2f(Yb[64 + y][2 * v]);
        T2[y][2 * v]     = f2b(Tr);
        T2[y][2 * v + 1] = f2b(Ti);
    }
    __syncthreads();

    float wreg[9]; float bias = 0.f;
    if (unit == 0) {
        const float* svp = skvp + (long)b * 2 * kCN + kCN + (long)c * kN;
        for (int i = tid; i < 58 * 65; i += 256) {
            int y = i / 65, x = i - y * 65;
            if (y == 0 || y == 57 || x == 0 || x >= 57) ((float*)svs)[i] = 0.f;
        }
        for (int i = tid; i < kN; i += 256) {
            int y = i / 56, x = i - y * 56;
            svs[y + 1][x + 1] = svp[i];
        }
#pragma unroll
        for (int j = 0; j < 9; ++j) wreg[j] = dww[c * 9 + j];
        bias = dwb[c];
    }

    float4v acc2[4];
#pragma unroll
    for (int n = 0; n < 4; ++n) acc2[n] = (float4v){0.f, 0.f, 0.f, 0.f};
#pragma unroll
    for (int ks = 0; ks < 2; ++ks) {
        Frag a;
        a.u4 = *(const uint4*)(tw + TW2I + (wave * 16 + ln) * 64 + ks * 32 + qd * 8);
#pragma unroll
        for (int n = 0; n < 4; ++n) {
            Frag bb;
            bb.u4 = *(const uint4*)&T2[n * 16 + ln][ks * 32 + qd * 8];
            acc2[n] = __builtin_amdgcn_mfma_f32_16x16x32_bf16(a.s, bb.s, acc2[n], 0, 0, 0);
        }
    }
    __syncthreads();

    float* outd = dst + (long)ch * kN;
#pragma unroll
    for (int n = 0; n < 4; ++n) {
        int y = n * 16 + ln;
        if (y < 56) {
#pragma unroll
            for (int r = 0; r < 4; ++r) {
                int x = wave * 16 + qd * 4 + r;
                if (x < 56) {
                    int e = y * 56 + x;
                    if (unit == 0) {
                        float s = bias;
                        s = fmaf(wreg[0], svs[y][x],     s);
                        s = fmaf(wreg[1], svs[y][x + 1], s);
                        s = fmaf(wreg[2], svs[y][x + 2], s);
                        s = fmaf(wreg[3], svs[y + 1][x],     s);
                        s = fmaf(wreg[4], svs[y + 1][x + 1], s);
                        s = fmaf(wreg[5], svs[y + 1][x + 2], s);
                        s = fmaf(wreg[6], svs[y + 2][x],     s);
                        s = fmaf(wreg[7], svs[y + 2][x + 1], s);
                        s = fmaf(wreg[8], svs[y + 2][x + 2], s);
                        outd[e] = fmaf(acc2[n][r], svs[y + 1][x + 1], s);
                    } else {
                        outd[e] = acc2[n][r];     // pure store (vres), combine adds xattn
                    }
                }
            }
        }
    }
}

// ---------------------------------------------------------------------------
// Attention body (k-split x4, software-pipelined, XCD-swizzled; smem 10240 B)
// ---------------------------------------------------------------------------
__device__ void attn_body(char* smem, int abi,
                          const float* __restrict__ tq,
                          const unsigned short* __restrict__ Kp,
                          const unsigned short* __restrict__ Vp,
                          float* __restrict__ Op, float* __restrict__ lp)
{
    const int xcd = abi & 7;
    const int t = abi >> 3;             // 0..199
    const int gsel = (t >= 100) ? 1 : 0;
    const int r0 = t - gsel * 100;      // 0..99
    const int grpId = (gsel << 3) | xcd;
    const int b = grpId >> 3, h = grpId & 7;
    const int sp = r0 / 25;
    const int q0 = (r0 % 25) * 128;
    const int tid = threadIdx.x;
    const int wave = tid >> 6, lane = tid & 63;
    const int qd = lane >> 4, ln = lane & 15;
    const int i0 = (sp == 0) ? 0 : (12 * sp + 1);
    const int i1 = 12 * sp + 13;

    const float* qb = tq + (long)b * kCN + (long)h * kHD * kN;
    const unsigned short* KpB = Kp + (long)(b * 8 + h) * 196 * 512 + ln * 32 + qd * 8;
    const unsigned short* VpB = Vp + (long)(b * 8 + h) * 49 * 2048 + ln * 32 + qd * 8;

    unsigned short* PsW = (unsigned short*)smem + wave * (32 * 40);

    const float qscale = kAttScale * kLog2e;
    Frag qf[2];
#pragma unroll
    for (int qt = 0; qt < 2; ++qt) {
        int qg = q0 + wave * 32 + qt * 16 + ln;
        bool qv = qg < kN;
#pragma unroll
        for (int j = 0; j < 8; ++j) {
            int d = qd * 8 + j;
            float v = qv ? qb[(long)d * kN + qg] * qscale : 0.f;
            qf[qt].u[j] = f2b(v);
        }
    }

    float4v o[2][2];
#pragma unroll
    for (int qt = 0; qt < 2; ++qt)
#pragma unroll
        for (int dh = 0; dh < 2; ++dh) o[qt][dh] = (float4v){0.f, 0.f, 0.f, 0.f};
    float lsum[2] = {0.f, 0.f};

    unsigned W[4][2][2];
    Frag ka[4];
#pragma unroll
    for (int m = 0; m < 4; ++m)
        ka[m].u4 = *(const uint4*)(KpB + (long)(4 * i0 + m) * 512);

    auto computeW = [&]() {
#pragma unroll
        for (int m = 0; m < 4; ++m) {
            float4v s0 = __builtin_amdgcn_mfma_f32_16x16x32_bf16(
                ka[m].s, qf[0].s, (float4v){0.f, 0.f, 0.f, 0.f}, 0, 0, 0);
            float4v s1 = __builtin_amdgcn_mfma_f32_16x16x32_bf16(
                ka[m].s, qf[1].s, (float4v){0.f, 0.f, 0.f, 0.f}, 0, 0, 0);
            float a0 = __builtin_amdgcn_exp2f(s0[0]);
            float a1 = __builtin_amdgcn_exp2f(s0[1]);
            float a2 = __builtin_amdgcn_exp2f(s0[2]);
            float a3 = __builtin_amdgcn_exp2f(s0[3]);
            lsum[0] += (a0 + a1) + (a2 + a3);
            W[m][0][0] = pk_trunc(a0, a1);
            W[m][0][1] = pk_trunc(a2, a3);
            float b0 = __builtin_amdgcn_exp2f(s1[0]);
            float b1 = __builtin_amdgcn_exp2f(s1[1]);
            float b2 = __builtin_amdgcn_exp2f(s1[2]);
            float b3 = __builtin_amdgcn_exp2f(s1[3]);
            lsum[1] += (b0 + b1) + (b2 + b3);
            W[m][1][0] = pk_trunc(b0, b1);
            W[m][1][1] = pk_trunc(b2, b3);
        }
    };

    computeW();
    if (i0 + 1 < i1) {
#pragma unroll
        for (int m = 0; m < 4; ++m)
            ka[m].u4 = *(const uint4*)(KpB + (long)(4 * (i0 + 1) + m) * 512);
    }

    for (int i = i0; i < i1; ++i) {
        Frag va[2][2];
#pragma unroll
        for (int g = 0; g < 2; ++g)
#pragma unroll
            for (int dh = 0; dh < 2; ++dh)
                va[g][dh].u4 = *(const uint4*)(VpB + (long)i * 2048 + (g * 2 + dh) * 512);

#pragma unroll
        for (int m = 0; m < 4; ++m)
#pragma unroll
            for (int qt = 0; qt < 2; ++qt)
                *(uint2*)&PsW[(qt * 16 + ln) * 40 + m * 16 + qd * 4] =
                    make_uint2(W[m][qt][0], W[m][qt][1]);

        if (i + 1 < i1) {
            computeW();
            if (i + 2 < i1) {
#pragma unroll
                for (int m = 0; m < 4; ++m)
                    ka[m].u4 = *(const uint4*)(KpB + (long)(4 * (i + 2) + m) * 512);
            }
        }

#pragma unroll
        for (int g = 0; g < 2; ++g) {
            Frag pa[2];
#pragma unroll
            for (int qt = 0; qt < 2; ++qt)
                pa[qt].u4 = *(const uint4*)&PsW[(qt * 16 + ln) * 40 + g * 32 + qd * 8];
#pragma unroll
            for (int qt = 0; qt < 2; ++qt)
#pragma unroll
                for (int dh = 0; dh < 2; ++dh)
                    o[qt][dh] = __builtin_amdgcn_mfma_f32_16x16x32_bf16(
                        pa[qt].s, va[g][dh].s, o[qt][dh], 0, 0, 0);
        }
    }

    const long grp = (long)(sp * 16 + b * 8 + h);
#pragma unroll
    for (int qt = 0; qt < 2; ++qt) {
        lsum[qt] += __shfl_xor(lsum[qt], 16, 64);
        lsum[qt] += __shfl_xor(lsum[qt], 32, 64);
        if (qd == 0)
            lp[grp * 3200 + q0 + wave * 32 + qt * 16 + ln] = lsum[qt];
#pragma unroll
        for (int dh = 0; dh < 2; ++dh)
#pragma unroll
            for (int r = 0; r < 4; ++r) {
                int q = q0 + wave * 32 + qt * 16 + qd * 4 + r;
                Op[(grp * 3200 + q) * 32 + dh * 16 + ln] = o[qt][dh][r];
            }
    }
}

// ---------------------------------------------------------------------------
// Mega dispatch 3: inverse DFTs + attention, interleaved (2624 blocks).
// Period 328 = 128 inv + 200 attn (×8 periods). 328%8==0 and 128%8==0 so
// attn-local index ≡ blockIdx (mod 8) — XCD swizzle preserved.
// ---------------------------------------------------------------------------
__global__ __launch_bounds__(256, 4)
void inv_attn_kernel(const float* __restrict__ fQ, const float* __restrict__ fK,
                     const float* __restrict__ fV, const float* __restrict__ cw,
                     float* __restrict__ dst1, float* __restrict__ dst2,
                     const float* __restrict__ skvp, const float* __restrict__ dww,
                     const float* __restrict__ dwb, const unsigned short* __restrict__ tw,
                     const float* __restrict__ tq,
                     const unsigned short* __restrict__ Kp,
                     const unsigned short* __restrict__ Vp,
                     float* __restrict__ Op, float* __restrict__ lp)
{
    __shared__ __align__(16) char smem[27648];
    const int per = blockIdx.x / 328;
    const int off = blockIdx.x % 328;
    if (off < 128)
        dft_inv_body(smem, per * 128 + off, fQ, fK, fV, cw, dst1, dst2, skvp, dww, dwb, tw);
    else
        attn_body(smem, per * 200 + (off - 128), tq, Kp, Vp, Op, lp);
}

// ---------------------------------------------------------------------------
// Combine 4 k-split partials, normalize, transpose, ADD into xo (holds vres).
// ---------------------------------------------------------------------------
__global__ __launch_bounds__(256)
void attn_combine_kernel(const float* __restrict__ Op, const float* __restrict__ lp,
                         float* __restrict__ xo)
{
    const int qc = blockIdx.x, bh = blockIdx.y;
    const int b = bh >> 3, h = bh & 7;
    const int q0 = qc * 64;
    __shared__ float T[32][65];
    const int tid = threadIdx.x;

    for (int i = tid; i < 64 * 32; i += 256) {
        int ql = i >> 5, d = i & 31;
        float ov = 0.f, l = 0.f;
#pragma unroll
        for (int s = 0; s < 4; ++s) {
            long g = (long)(s * 16 + bh);
            ov += Op[(g * 3200 + q0 + ql) * 32 + d];
            l  += lp[g * 3200 + q0 + ql];
        }
        T[d][ql] = ov / l;
    }
    __syncthreads();
    for (int i = tid; i < 32 * 64; i += 256) {
        int d = i >> 6, ql = i & 63;
        xo[(long)b * kCN + (long)(h * kHD + d) * kN + q0 + ql] += T[d][ql];
    }
}

// ---------------------------------------------------------------------------
// Output projections (dual GEMM, different inputs) -> gcat
// ---------------------------------------------------------------------------
__global__ __launch_bounds__(256)
void gemm_fused(const float* __restrict__ W0, const float* __restrict__ W1,
                const float* __restrict__ X0, const float* __restrict__ X1,
                const float* __restrict__ b0, const float* __restrict__ b1,
                float* __restrict__ Y0, float* __restrict__ Y1,
                int oHalf, int CI, long xbs, long ybs, int oOffset)
{
    __shared__ __align__(16) char smem[15360];
    const int b  = blockIdx.z;
    const int sel = blockIdx.y >= oHalf;
    const int o0 = (sel ? blockIdx.y - oHalf : blockIdx.y) * 64;
    const int oY = o0 + (sel ? oOffset : 0);
    gemm_bias_body(smem, sel ? W1 : W0, (sel ? X1 : X0) + (long)b * xbs,
                   sel ? b1 : b0, (sel ? Y1 : Y0) + (long)b * ybs,
                   o0, oY, blockIdx.x * 128, CI);
}

// ---------------------------------------------------------------------------
// BN+ReLU GEMM for the gate hidden layer (CI=512)
// ---------------------------------------------------------------------------
__global__ __launch_bounds__(256)
void gemm_bn_kernel(const float* __restrict__ Wm, const float* __restrict__ X,
                    const float* __restrict__ gamma, const float* __restrict__ beta,
                    float* __restrict__ Y, int CI, long xbs, long ybs)
{
    const int b  = blockIdx.z;
    const int o0 = blockIdx.y * 64;
    const int n0 = blockIdx.x * 128;
    const float* Xb = X + (long)b * xbs;
    float* Yb = Y + (long)b * ybs;

    __shared__ __align__(16) unsigned short Wt[64][40];
    __shared__ __align__(16) unsigned short Xt[128][40];

    const int tid = threadIdx.x;
    const int wave = tid >> 6, lane = tid & 63;
    const int ln = lane & 15, qd = lane >> 4;
    const int wy = wave >> 1, wx = wave & 1;

    const int ow = tid >> 2, kcw = tid & 3;
    const int nx = tid & 127, kcx = tid >> 7;
    const bool xvalid = (n0 + nx) < kN;

    float4v acc[2][4];
#pragma unroll
    for (int i = 0; i < 2; ++i)
#pragma unroll
        for (int j = 0; j < 4; ++j) acc[i][j] = (float4v){0.f, 0.f, 0.f, 0.f};

    float wpre[8], xpre[16];
    {
        const float* ws = Wm + (long)(o0 + ow) * CI + kcw * 8;
        *(float4*)&wpre[0] = *(const float4*)ws;
        *(float4*)&wpre[4] = *(const float4*)(ws + 4);
#pragma unroll
        for (int j = 0; j < 16; ++j)
            xpre[j] = xvalid ? Xb[(long)(kcx * 16 + j) * kN + n0 + nx] : 0.f;
    }

    for (int k0 = 0; k0 < CI; k0 += 32) {
        *(uint4*)&Wt[ow][kcw * 8]      = pk8(wpre);
        *(uint4*)&Xt[nx][kcx * 16]     = pk8(xpre);
        *(uint4*)&Xt[nx][kcx * 16 + 8] = pk8(xpre + 8);
        __syncthreads();

        if (k0 + 32 < CI) {
            const float* ws = Wm + (long)(o0 + ow) * CI + k0 + 32 + kcw * 8;
            *(float4*)&wpre[0] = *(const float4*)ws;
            *(float4*)&wpre[4] = *(const float4*)(ws + 4);
#pragma unroll
            for (int j = 0; j < 16; ++j)
                xpre[j] = xvalid ? Xb[(long)(k0 + 32 + kcx * 16 + j) * kN + n0 + nx] : 0.f;
        }

        Frag af[2], bf4[4];
#pragma unroll
        for (int mt = 0; mt < 2; ++mt)
            af[mt].u4 = *(const uint4*)&Wt[wy * 32 + mt * 16 + ln][qd * 8];
#pragma unroll
        for (int nt = 0; nt < 4; ++nt)
            bf4[nt].u4 = *(const uint4*)&Xt[wx * 64 + nt * 16 + ln][qd * 8];
#pragma unroll
        for (int mt = 0; mt < 2; ++mt)
#pragma unroll
            for (int nt = 0; nt < 4; ++nt)
                acc[mt][nt] = __builtin_amdgcn_mfma_f32_16x16x32_bf16(
                    af[mt].s, bf4[nt].s, acc[mt][nt], 0, 0, 0);
        __syncthreads();
    }

    const float rs = rsqrtf(1.0f + 1e-5f);
#pragma unroll
    for (int mt = 0; mt < 2; ++mt) {
        const int ob = o0 + wy * 32 + mt * 16 + qd * 4;
#pragma unroll
        for (int nt = 0; nt < 4; ++nt) {
            const int n = n0 + wx * 64 + nt * 16 + ln;
            if (n < kN) {
#pragma unroll
                for (int r = 0; r < 4; ++r) {
                    const int o = ob + r;
                    float v = fmaxf(fmaf(acc[mt][nt][r], gamma[o] * rs, beta[o]), 0.f);
                    Yb[(long)o * kN + n] = v;
                }
            }
        }
    }
}

// ---------------------------------------------------------------------------
// Fused gate + blend.
// ---------------------------------------------------------------------------
__global__ __launch_bounds__(256)
void gateblend_kernel(const float* __restrict__ hbuf, const float* __restrict__ w2,
                      const float* __restrict__ b2, const float* __restrict__ gcat,
                      float* __restrict__ out)
{
    const int n0 = blockIdx.x * 64;
    const int b = blockIdx.y;
    const int lane = threadIdx.x & 63;
    const int g = threadIdx.x >> 6;
    const float* hb = hbuf + (long)b * kCN + n0 + lane;
    float s = 0.f;
#pragma unroll 8
    for (int c = g * 64; c < g * 64 + 64; ++c)
        s = fmaf(w2[c], hb[(long)c * kN], s);
    __shared__ float red[4][64];
    __shared__ float sgate[64];
    red[g][lane] = s;
    __syncthreads();
    if (g == 0) {
        float t = red[0][lane] + red[1][lane] + red[2][lane] + red[3][lane];
        sgate[lane] = 1.f / (1.f + __expf(-(t + b2[0])));
    }
    __syncthreads();
    const float gt = sgate[lane];
    const float* osp = gcat + (long)b * 2 * kCN + n0 + lane;
    const float* otp = osp + kCN;
    float* op = out + (long)b * kCN + n0 + lane;
    for (int c = g; c < kC; c += 4) {
        float os = osp[(long)c * kN];
        float ot = otp[(long)c * kN];
        op[(long)c * kN] = gt * os + (1.f - gt) * ot;
    }
}

// ---------------------------------------------------------------------------
extern "C" void kernel_launch(void* const* d_in, const int* in_sizes, int n_in,
                              void* d_out, int out_size, void* d_ws, size_t ws_size,
                              hipStream_t stream)
{
    const float* x      = (const float*)d_in[0];
    const float* ctx    = (const float*)d_in[1];
    const float* s_q_w  = (const float*)d_in[2];
    const float* s_kv_w = (const float*)d_in[3];
    const float* s_p_w  = (const float*)d_in[4];
    const float* s_p_b  = (const float*)d_in[5];
    const float* s_dw_w = (const float*)d_in[6];
    const float* s_dw_b = (const float*)d_in[7];
    const float* t_q_w  = (const float*)d_in[8];
    const float* t_kv_w = (const float*)d_in[9];
    const float* t_p_w  = (const float*)d_in[10];
    const float* t_p_b  = (const float*)d_in[11];
    const float* t_cw   = (const float*)d_in[12];
    const float* g_w1   = (const float*)d_in[13];
    const float* g_bn_g = (const float*)d_in[14];
    const float* g_bn_b = (const float*)d_in[15];
    const float* g_w2   = (const float*)d_in[16];
    const float* g_b2   = (const float*)d_in[17];
    float* out = (float*)d_out;

    float* ws = (float*)d_ws;
    const long SPEC2 = (long)kB * kC * kSpec * 2;
    float* sq   = ws;                    // B*C*N   (sq -> vres -> tpre)
    float* skv  = sq   + kB * kCN;       // B*2C*N
    float* tq   = skv  + kB * 2 * kCN;   // B*C*N
    float* tkv  = tq   + kB * kCN;       // B*2C*N  (later: h)
    float* vloc = tkv  + kB * 2 * kCN;   // B*C*N   (spre result)
    float* fQ   = vloc + kB * kCN;
    float* fK   = fQ   + SPEC2;
    float* fV   = fK   + SPEC2;
    float* gcat = fV   + SPEC2;          // B*2C*N : [os ; ot]
    float* gate = gcat + kB * 2 * kCN;   // B*N (unused slot, kept for layout)
    unsigned short* tw = (unsigned short*)(gate + kB * kN);  // twiddles
    unsigned short* Kp = tw + TWTOT;                         // 16*196*512 u16
    unsigned short* Vp = Kp + (long)16 * 196 * 512;          // 16*49*2048 u16
    float* Opart = (float*)(Vp + (long)16 * 49 * 2048);      // 64*3200*32 f32
    float* lpart = Opart + (long)64 * 3200 * 32;             // 64*3200 f32

    dim3 blk(256, 1, 1);

    // 1: twiddle + all 4 projection GEMMs
    init_proj_kernel<<<dim3(1296), blk, 0, stream>>>(
        tw, x, ctx, s_q_w, t_q_w, s_kv_w, t_kv_w, sq, tq, skv, tkv);

    // 2: three forward DFTs + attention K/V prepack
    fwd3_prepack_kernel<<<dim3(3 * kB * kC + kB * kNH * 49), blk, 0, stream>>>(
        sq, skv, tkv + kCN, fQ, fK, fV, tw, tkv, Kp, Vp);

    // 3: both inverse DFTs + attention (independent; interleaved co-schedule)
    inv_attn_kernel<<<dim3(2624), blk, 0, stream>>>(
        fQ, fK, fV, t_cw, vloc, sq, skv, s_dw_w, s_dw_b, tw,
        tq, Kp, Vp, Opart, lpart);

    // 4: combine k-split partials -> sq += xattn (sq holds vres)
    attn_combine_kernel<<<dim3(49, 16), blk, 0, stream>>>(Opart, lpart, sq);

    // 5: both output projections -> gcat
    gemm_fused<<<dim3(25, 8, kB), blk, 0, stream>>>(
        s_p_w, t_p_w, vloc, sq, s_p_b, t_p_b, gcat, gcat, 4, kC, kCN, 2 * kCN, 256);

    // 6: gate hidden GEMM (BN+ReLU)
    gemm_bn_kernel<<<dim3(25, 4, kB), blk, 0, stream>>>(g_w1, gcat, g_bn_g, g_bn_b, tkv, 2 * kC, 2 * kCN, kCN);

    // 7: gate + blend
    gateblend_kernel<<<dim3(49, kB), blk, 0, stream>>>(tkv, g_w2, g_b2, gcat, out);
}

// Round 16
// 263.465 us; speedup vs baseline: 1.0123x; 1.0123x over previous
//
#include <hip/hip_runtime.h>

namespace {
constexpr int kB = 2;
constexpr int kC = 256;
constexpr int kH = 56;
constexpr int kW = 56;
constexpr int kN = kH * kW;        // 3136
constexpr int kNH = 8;
constexpr int kHD = 32;
constexpr int kNF = kW / 2 + 1;    // 29
constexpr int kSpec = kH * kNF;    // 1624
constexpr long kCN = (long)kC * kN;        // 802816
constexpr float kAttScale = 0.17677669529663687f;   // 32^-0.5
constexpr float kLog2e = 1.4426950408889634f;
constexpr float kAng = 6.283185307179586f / 56.0f;  // 2*pi/56
// twiddle table offsets in u16 units
constexpr int TW1F = 0;            // [128][64]
constexpr int TW2F = 8192;         // [64][64]
constexpr int TW1I = 12288;        // [128][64]
constexpr int TW2I = 20480;        // [64][64]
constexpr int TWTOT = 24576;
}

typedef __attribute__((ext_vector_type(8))) short short8;
typedef __attribute__((ext_vector_type(4))) float float4v;

union Frag {
    short8 s;
    unsigned short u[8];
    uint2 u2[2];
    uint4 u4;
};

__device__ __forceinline__ unsigned short f2b(float f) {
    unsigned u = __float_as_uint(f);
    return (unsigned short)((u + 0x7FFFu + ((u >> 16) & 1u)) >> 16);
}
__device__ __forceinline__ float b2f(unsigned short u) {
    return __uint_as_float((unsigned)u << 16);
}
__device__ __forceinline__ unsigned f2b_pk(float a, float b) {
    unsigned ua = __float_as_uint(a); ua = (ua + 0x7FFFu + ((ua >> 16) & 1u)) >> 16;
    unsigned ub = __float_as_uint(b); ub = (ub + 0x7FFFu + ((ub >> 16) & 1u)) >> 16;
    return ua | (ub << 16);
}
__device__ __forceinline__ unsigned pk_trunc(float a, float b) {
    return (__float_as_uint(a) >> 16) | (__float_as_uint(b) & 0xFFFF0000u);
}
__device__ __forceinline__ uint4 pk8(const float* v) {
    return make_uint4(f2b_pk(v[0], v[1]), f2b_pk(v[2], v[3]),
                      f2b_pk(v[4], v[5]), f2b_pk(v[6], v[7]));
}

// ---------------------------------------------------------------------------
// Twiddle body (bf16 tables into d_ws)
// ---------------------------------------------------------------------------
__device__ void twiddle_body(int blk, unsigned short* __restrict__ tw)
{
    int idx = blk * 256 + threadIdx.x;
    if (idx >= TWTOT) return;
    float val = 0.f;
    if (idx < TW2F) {                       // TW1F
        int r = idx >> 6, c = idx & 63;
        if (c < 56) {
            if (r < 56)       val = cosf(kAng * (float)((r * c) % 56));
            else if (r < 112) val = sinf(kAng * (float)(((r - 56) * c) % 56));
        }
    } else if (idx < TW1I) {                // TW2F
        int t = idx - TW2F; int r = t >> 6, c = t & 63;
        if (c < 56) {
            if (r < 29)                  val = cosf(kAng * (float)((r * c) % 56));
            else if (r >= 32 && r < 61)  val = sinf(kAng * (float)(((r - 32) * c) % 56));
        }
    } else if (idx < TW2I) {                // TW1I
        int t = idx - TW1I; int r = t >> 6, c = t & 63;
        if (c < 56) {
            if (r < 56)                  val = cosf(kAng * (float)((r * c) % 56));
            else if (r >= 64 && r < 120) val = sinf(kAng * (float)(((r - 64) * c) % 56));
        }
    } else {                                // TW2I
        int t = idx - TW2I; int x = t >> 6, c = t & 63;
        if (x < 56 && c < 58) {
            int v = c >> 1;
            float wv = ((v == 0) || (v == 28)) ? 1.f : 2.f;
            float a = kAng * (float)((v * x) % 56);
            val = (c & 1) ? (-wv * sinf(a)) : (wv * cosf(a));
        }
    }
    tw[idx] = f2b(val);
}

// ---------------------------------------------------------------------------
// GEMM body (bias epilogue). Weight/bias rows: o0; output rows: oY.
// smem: Wt[64][40] @0 (5120 B) + Xt[128][40] @5120 (10240 B) = 15360 B
// ---------------------------------------------------------------------------
__device__ void gemm_bias_body(char* smem, const float* __restrict__ Wm,
                               const float* __restrict__ Xb,
                               const float* __restrict__ bias, float* __restrict__ Yb,
                               int o0, int oY, int n0, int CI)
{
    unsigned short (*Wt)[40] = (unsigned short(*)[40])smem;
    unsigned short (*Xt)[40] = (unsigned short(*)[40])(smem + 5120);

    const int tid = threadIdx.x;
    const int wave = tid >> 6, lane = tid & 63;
    const int ln = lane & 15, qd = lane >> 4;
    const int wy = wave >> 1, wx = wave & 1;

    const int ow = tid >> 2, kcw = tid & 3;
    const int nx = tid & 127, kcx = tid >> 7;
    const bool xvalid = (n0 + nx) < kN;

    float4v acc[2][4];
#pragma unroll
    for (int i = 0; i < 2; ++i)
#pragma unroll
        for (int j = 0; j < 4; ++j) acc[i][j] = (float4v){0.f, 0.f, 0.f, 0.f};

    float wpre[8], xpre[16];
    {
        const float* ws = Wm + (long)(o0 + ow) * CI + kcw * 8;
        *(float4*)&wpre[0] = *(const float4*)ws;
        *(float4*)&wpre[4] = *(const float4*)(ws + 4);
#pragma unroll
        for (int j = 0; j < 16; ++j)
            xpre[j] = xvalid ? Xb[(long)(kcx * 16 + j) * kN + n0 + nx] : 0.f;
    }

    for (int k0 = 0; k0 < CI; k0 += 32) {
        *(uint4*)&Wt[ow][kcw * 8]      = pk8(wpre);
        *(uint4*)&Xt[nx][kcx * 16]     = pk8(xpre);
        *(uint4*)&Xt[nx][kcx * 16 + 8] = pk8(xpre + 8);
        __syncthreads();

        if (k0 + 32 < CI) {
            const float* ws = Wm + (long)(o0 + ow) * CI + k0 + 32 + kcw * 8;
            *(float4*)&wpre[0] = *(const float4*)ws;
            *(float4*)&wpre[4] = *(const float4*)(ws + 4);
#pragma unroll
            for (int j = 0; j < 16; ++j)
                xpre[j] = xvalid ? Xb[(long)(k0 + 32 + kcx * 16 + j) * kN + n0 + nx] : 0.f;
        }

        Frag af[2], bf4[4];
#pragma unroll
        for (int mt = 0; mt < 2; ++mt)
            af[mt].u4 = *(const uint4*)&Wt[wy * 32 + mt * 16 + ln][qd * 8];
#pragma unroll
        for (int nt = 0; nt < 4; ++nt)
            bf4[nt].u4 = *(const uint4*)&Xt[wx * 64 + nt * 16 + ln][qd * 8];
#pragma unroll
        for (int mt = 0; mt < 2; ++mt)
#pragma unroll
            for (int nt = 0; nt < 4; ++nt)
                acc[mt][nt] = __builtin_amdgcn_mfma_f32_16x16x32_bf16(
                    af[mt].s, bf4[nt].s, acc[mt][nt], 0, 0, 0);
        __syncthreads();
    }

#pragma unroll
    for (int mt = 0; mt < 2; ++mt) {
        const int obL = o0 + wy * 32 + mt * 16 + qd * 4;
        const int obY = oY + wy * 32 + mt * 16 + qd * 4;
#pragma unroll
        for (int nt = 0; nt < 4; ++nt) {
            const int n = n0 + wx * 64 + nt * 16 + ln;
            if (n < kN) {
#pragma unroll
                for (int r = 0; r < 4; ++r) {
                    float v = acc[mt][nt][r];
                    if (bias) v += bias[obL + r];
                    Yb[(long)(obY + r) * kN + n] = v;
                }
            }
        }
    }
}

// ---------------------------------------------------------------------------
// Mega dispatch 1: twiddle init + all 4 projection GEMMs (1296 blocks).
// [0,96): twiddle; [96,496): q-projections; [496,1296): kv-projections.
// ---------------------------------------------------------------------------
__global__ __launch_bounds__(256)
void init_proj_kernel(unsigned short* __restrict__ tw,
                      const float* __restrict__ x, const float* __restrict__ ctx,
                      const float* __restrict__ s_q_w, const float* __restrict__ t_q_w,
                      const float* __restrict__ s_kv_w, const float* __restrict__ t_kv_w,
                      float* __restrict__ sq, float* __restrict__ tq,
                      float* __restrict__ skv, float* __restrict__ tkv)
{
    __shared__ __align__(16) char smem[15360];
    int bi = blockIdx.x;
    if (bi < 96) { twiddle_body(bi, tw); return; }
    bi -= 96;
    if (bi < 400) {
        // q-projections: 2b x 8y x 25n
        int b = bi / 200, rem = bi % 200;
        int y = rem / 25, xb = rem % 25;
        int sel = y >= 4;
        int o0 = (sel ? y - 4 : y) * 64;
        gemm_bias_body(smem, sel ? t_q_w : s_q_w, (x + (long)b * kCN), nullptr,
                       (sel ? tq : sq) + (long)b * kCN, o0, o0, xb * 128, kC);
    } else {
        bi -= 400;
        int b = bi / 400, rem = bi % 400;
        int y = rem / 25, xb = rem % 25;
        int sel = y >= 8;
        int o0 = (sel ? y - 8 : y) * 64;
        gemm_bias_body(smem, sel ? t_kv_w : s_kv_w, (ctx + (long)b * kCN), nullptr,
                       (sel ? tkv : skv) + (long)b * 2 * kCN, o0, o0, xb * 128, kC);
    }
}

// ---------------------------------------------------------------------------
// Forward 2D DFT body — transpose-free (round 15).
// Phase 1: H[y][vc] = sum_x img[y][x]*TW2F[vc][x]
// Phase 2: D2[uc][vc] = sum_y TW1F[uc][y]*H[y][vc]
// Qr = D2[u][v] - D2[56+u][32+v]; Qi = -D2[56+u][v] - D2[u][32+v]
// LDS: HT[64][72] @0 | imgR[64][72] @9216 | YT[64][136] @9216 overlay = 26624 B
// ---------------------------------------------------------------------------
__device__ void dft_fwd_body(char* smem, int bx,
                             const float* __restrict__ s0, const float* __restrict__ s1,
                             const float* __restrict__ s2, float* __restrict__ d0,
                             float* __restrict__ d1, float* __restrict__ d2,
                             const unsigned short* __restrict__ tw)
{
    const int which = bx >> 9, ch = bx & 511;
    const int b = ch >> 8, c = ch & 255;
    const float* src; long stride; float* spec;
    if (which == 0)      { src = s0; stride = kCN;     spec = d0; }
    else if (which == 1) { src = s1; stride = 2 * kCN; spec = d1; }
    else                 { src = s2; stride = 2 * kCN; spec = d2; }
    const float* img = src + (long)b * stride + (long)c * kN;

    unsigned short (*HT)[72]   = (unsigned short(*)[72])smem;            // 9216
    unsigned short (*imgR)[72] = (unsigned short(*)[72])(smem + 9216);   // 9216
    unsigned short (*YT)[136]  = (unsigned short(*)[136])(smem + 9216);  // 17408 overlay

    const int tid = threadIdx.x;
    const int wave = tid >> 6, lane = tid & 63;
    const int ln = lane & 15, qd = lane >> 4;

    for (int i = tid; i < 64 * 72; i += 256) {
        int r = i / 72, cc = i - r * 72;
        if (r >= 56 || cc >= 56) imgR[r][cc] = 0;
    }
    for (int e = tid; e < 784; e += 256) {
        int y = e / 14, x0 = (e % 14) * 4;
        float4 v4 = *(const float4*)(img + y * 56 + x0);
        *(uint2*)&imgR[y][x0] = make_uint2(f2b_pk(v4.x, v4.y), f2b_pk(v4.z, v4.w));
    }
    __syncthreads();

    float4v acc1[4];
#pragma unroll
    for (int n = 0; n < 4; ++n) acc1[n] = (float4v){0.f, 0.f, 0.f, 0.f};
#pragma unroll
    for (int ks = 0; ks < 2; ++ks) {
        Frag a;
        a.u4 = *(const uint4*)&imgR[wave * 16 + ln][ks * 32 + qd * 8];
#pragma unroll
        for (int nt = 0; nt < 4; ++nt) {
            Frag bb;
            bb.u4 = *(const uint4*)(tw + TW2F + (nt * 16 + ln) * 64 + ks * 32 + qd * 8);
            acc1[nt] = __builtin_amdgcn_mfma_f32_16x16x32_bf16(a.s, bb.s, acc1[nt], 0, 0, 0);
        }
    }
#pragma unroll
    for (int nt = 0; nt < 4; ++nt)
        *(uint2*)&HT[nt * 16 + ln][wave * 16 + qd * 4] =
            make_uint2(f2b_pk(acc1[nt][0], acc1[nt][1]),
                       f2b_pk(acc1[nt][2], acc1[nt][3]));
    __syncthreads();

    float4v acc2[2][4];
#pragma unroll
    for (int m = 0; m < 2; ++m)
#pragma unroll
        for (int n = 0; n < 4; ++n) acc2[m][n] = (float4v){0.f, 0.f, 0.f, 0.f};
#pragma unroll
    for (int ks = 0; ks < 2; ++ks) {
        Frag a[2], bb[4];
#pragma unroll
        for (int mt = 0; mt < 2; ++mt)
            a[mt].u4 = *(const uint4*)(tw + TW1F + ((2 * wave + mt) * 16 + ln) * 64 + ks * 32 + qd * 8);
#pragma unroll
        for (int nt = 0; nt < 4; ++nt)
            bb[nt].u4 = *(const uint4*)&HT[nt * 16 + ln][ks * 32 + qd * 8];
#pragma unroll
        for (int mt = 0; mt < 2; ++mt)
#pragma unroll
            for (int nt = 0; nt < 4; ++nt)
                acc2[mt][nt] = __builtin_amdgcn_mfma_f32_16x16x32_bf16(a[mt].s, bb[nt].s, acc2[mt][nt], 0, 0, 0);
    }
#pragma unroll
    for (int mt = 0; mt < 2; ++mt)
#pragma unroll
        for (int nt = 0; nt < 4; ++nt)
            *(uint2*)&YT[nt * 16 + ln][(2 * wave + mt) * 16 + qd * 4] =
                make_uint2(f2b_pk(acc2[mt][nt][0], acc2[mt][nt][1]),
                           f2b_pk(acc2[mt][nt][2], acc2[mt][nt][3]));
    __syncthreads();

    float2* outp = (float2*)spec + (long)ch * kSpec;
    for (int i = tid; i < kSpec; i += 256) {
        int u = i / kNF, v = i - u * kNF;
        float Qr = b2f(YT[v][u]) - b2f(YT[32 + v][56 + u]);
        float Qi = -b2f(YT[v][56 + u]) - b2f(YT[32 + v][u]);
        outp[i] = make_float2(Qr, Qi);
    }
}

// ---------------------------------------------------------------------------
// Attention K/V prepack body
// ---------------------------------------------------------------------------
__device__ void prepack_body(char* smem, int blk, const float* __restrict__ tkv,
                             unsigned short* __restrict__ Kp,
                             unsigned short* __restrict__ Vp)
{
    const int i = blk % 49;
    const int h = (blk / 49) & 7;
    const int b = blk / (49 * 8);
    const float* kb = tkv + (long)b * 2 * kCN + (long)h * kHD * kN;
    const float* vb = kb + kCN;
    const int tid = threadIdx.x;

    float (*Ks)[72] = (float(*)[72])smem;
#pragma unroll
    for (int j = 0; j < 8; ++j) {
        int e = tid + j * 256;
        int d = e >> 6, c = e & 63;
        Ks[d][c] = kb[(long)d * kN + i * 64 + c];
    }
    __syncthreads();
    {
        int tl = tid >> 6, lnn = (tid >> 2) & 15, qdd = tid & 3;
        float v[8];
#pragma unroll
        for (int j = 0; j < 8; ++j) v[j] = Ks[qdd * 8 + j][tl * 16 + lnn];
        unsigned short* dst = Kp + ((long)(b * 8 + h) * 196 + 4 * i + tl) * 512 + lnn * 32 + qdd * 8;
        *(uint4*)dst = pk8(v);
    }
    {
        int g = tid >> 7, dh = (tid >> 6) & 1, lnn = (tid >> 2) & 15, qdd = tid & 3;
        int d = dh * 16 + lnn;
        const float* src = vb + (long)d * kN + i * 64 + g * 32 + qdd * 8;
        float v[8];
        *(float4*)&v[0] = *(const float4*)src;
        *(float4*)&v[4] = *(const float4*)(src + 4);
        unsigned short* dst = Vp + ((long)(b * 8 + h) * 49 + i) * 2048 + ((g * 2 + dh) * 16 + lnn) * 32 + qdd * 8;
        *(uint4*)dst = pk8(v);
    }
}

// ---------------------------------------------------------------------------
// Mega dispatch 2: forward DFTs (1536) + K/V prepack (784), INTERLEAVED.
// Period 290 = 192 fwd + 98 prepack × 8 periods — mixes long barrier-heavy
// fwd blocks with short memory-only prepack blocks on every CU (round-12
// co-schedule lesson; round-15 showed the fwd body itself is not the pole).
// ---------------------------------------------------------------------------
__global__ __launch_bounds__(256)
void fwd3_prepack_kernel(const float* __restrict__ s0, const float* __restrict__ s1,
                         const float* __restrict__ s2, float* __restrict__ d0,
                         float* __restrict__ d1, float* __restrict__ d2,
                         const unsigned short* __restrict__ tw,
                         const float* __restrict__ tkv,
                         unsigned short* __restrict__ Kp, unsigned short* __restrict__ Vp)
{
    __shared__ __align__(16) char smem[26624];
    const int per = blockIdx.x / 290;
    const int off = blockIdx.x % 290;
    if (off < 192)
        dft_fwd_body(smem, per * 192 + off, s0, s1, s2, d0, d1, d2, tw);
    else
        prepack_body(smem, per * 98 + (off - 192), tkv, Kp, Vp);
}

// ---------------------------------------------------------------------------
// Inverse 2D DFT body (bf16 Yb; smem 27648 B)
// ---------------------------------------------------------------------------
__device__ void dft_inv_body(char* smem, int bx,
                             const float* __restrict__ fQ, const float* __restrict__ fK,
                             const float* __restrict__ fV, const float* __restrict__ cw,
                             float* __restrict__ dst1, float* __restrict__ dst2,
                             const float* __restrict__ skvp, const float* __restrict__ dww,
                             const float* __restrict__ dwb, const unsigned short* __restrict__ tw)
{
    const int unit = bx >> 9;
    const int ch = bx & 511;
    const int b = ch >> 8, c = ch & 255;
    unsigned short (*Pb)[72]  = (unsigned short(*)[72])smem;           // 9216
    unsigned short (*Yb)[72]  = (unsigned short(*)[72])(smem + 9216);  // 18432
    unsigned short (*T2)[72]  = (unsigned short(*)[72])smem;           // overlays Pb
    float (*svs)[65]          = (float(*)[65])(smem + 9216);           // overlays Yb

    const int tid = threadIdx.x;
    const int wave = tid >> 6, lane = tid & 63;
    const int ln = lane & 15, qd = lane >> 4;

    const float2* Pin; const float2* Min; float scale; float* dst;
    if (unit == 0) {
        Pin = (const float2*)fQ + (long)ch * kSpec;
        Min = (const float2*)fK + (long)ch * kSpec;
        scale = 1.0f / 175616.0f; dst = dst1;
    } else {
        Pin = (const float2*)fV + (long)ch * kSpec;
        Min = (const float2*)cw + (long)c * kSpec;
        scale = 1.0f / 3136.0f; dst = dst2;
    }

    for (int i = tid; i < 64 * 72; i += 256) {
        int r = i / 72, cc = i - r * 72;
        if (r >= 58 || cc >= 56) Pb[r][cc] = 0;
    }
    for (int i = tid; i < kSpec; i += 256) {
        int u = i / kNF, v = i - u * kNF;
        float2 p = Pin[i];
        float2 m = Min[i];
        float pr = (p.x * m.x - p.y * m.y) * scale;
        float pi = (p.x * m.y + p.y * m.x) * scale;
        Pb[2 * v][u]     = f2b(pr);
        Pb[2 * v + 1][u] = f2b(pi);
    }
    __syncthreads();

    float4v acc1[2][4];
#pragma unroll
    for (int m = 0; m < 2; ++m)
#pragma unroll
        for (int n = 0; n < 4; ++n) acc1[m][n] = (float4v){0.f, 0.f, 0.f, 0.f};
#pragma unroll
    for (int ks = 0; ks < 2; ++ks) {
        Frag a[2], bf[4];
#pragma unroll
        for (int m = 0; m < 2; ++m)
            a[m].u4 = *(const uint4*)(tw + TW1I + ((2 * wave + m) * 16 + ln) * 64 + ks * 32 + qd * 8);
#pragma unroll
        for (int n = 0; n < 4; ++n)
            bf[n].u4 = *(const uint4*)&Pb[n * 16 + ln][ks * 32 + qd * 8];
#pragma unroll
        for (int m = 0; m < 2; ++m)
#pragma unroll
            for (int n = 0; n < 4; ++n)
                acc1[m][n] = __builtin_amdgcn_mfma_f32_16x16x32_bf16(a[m].s, bf[n].s, acc1[m][n], 0, 0, 0);
    }
#pragma unroll
    for (int m = 0; m < 2; ++m)
#pragma unroll
        for (int n = 0; n < 4; ++n)
#pragma unroll
            for (int r = 0; r < 4; ++r)
                Yb[(2 * wave + m) * 16 + qd * 4 + r][n * 16 + ln] = f2b(acc1[m][n][r]);
    __syncthreads();

    for (int i = tid; i < 64 * 72; i += 256) {
        int r = i / 72, cc = i - r * 72;
        if (r >= 56 || cc >= 58) T2[r][cc] = 0;
    }
    __syncthreads();
    for (int i = tid; i < 56 * kNF; i += 256) {
        int y = i / kNF, v = i - y * kNF;
        float Tr = b2f(Yb[y][2 * v])     - b2f(Yb[64 + y][2 * v + 1]);
        float Ti = b2f(Yb[y][2 * v + 1]) + b2f(Yb[64 + y][2 * v]);
        T2[y][2 * v]     = f2b(Tr);
        T2[y][2 * v + 1] = f2b(Ti);
    }
    __syncthreads();

    float wreg[9]; float bias = 0.f;
    if (unit == 0) {
        const float* svp = skvp + (long)b * 2 * kCN + kCN + (long)c * kN;
        for (int i = tid; i < 58 * 65; i += 256) {
            int y = i / 65, x = i - y * 65;
            if (y == 0 || y == 57 || x == 0 || x >= 57) ((float*)svs)[i] = 0.f;
        }
        for (int i = tid; i < kN; i += 256) {
            int y = i / 56, x = i - y * 56;
            svs[y + 1][x + 1] = svp[i];
        }
#pragma unroll
        for (int j = 0; j < 9; ++j) wreg[j] = dww[c * 9 + j];
        bias = dwb[c];
    }

    float4v acc2[4];
#pragma unroll
    for (int n = 0; n < 4; ++n) acc2[n] = (float4v){0.f, 0.f, 0.f, 0.f};
#pragma unroll
    for (int ks = 0; ks < 2; ++ks) {
        Frag a;
        a.u4 = *(const uint4*)(tw + TW2I + (wave * 16 + ln) * 64 + ks * 32 + qd * 8);
#pragma unroll
        for (int n = 0; n < 4; ++n) {
            Frag bb;
            bb.u4 = *(const uint4*)&T2[n * 16 + ln][ks * 32 + qd * 8];
            acc2[n] = __builtin_amdgcn_mfma_f32_16x16x32_bf16(a.s, bb.s, acc2[n], 0, 0, 0);
        }
    }
    __syncthreads();

    float* outd = dst + (long)ch * kN;
#pragma unroll
    for (int n = 0; n < 4; ++n) {
        int y = n * 16 + ln;
        if (y < 56) {
#pragma unroll
            for (int r = 0; r < 4; ++r) {
                int x = wave * 16 + qd * 4 + r;
                if (x < 56) {
                    int e = y * 56 + x;
                    if (unit == 0) {
                        float s = bias;
                        s = fmaf(wreg[0], svs[y][x],     s);
                        s = fmaf(wreg[1], svs[y][x + 1], s);
                        s = fmaf(wreg[2], svs[y][x + 2], s);
                        s = fmaf(wreg[3], svs[y + 1][x],     s);
                        s = fmaf(wreg[4], svs[y + 1][x + 1], s);
                        s = fmaf(wreg[5], svs[y + 1][x + 2], s);
                        s = fmaf(wreg[6], svs[y + 2][x],     s);
                        s = fmaf(wreg[7], svs[y + 2][x + 1], s);
                        s = fmaf(wreg[8], svs[y + 2][x + 2], s);
                        outd[e] = fmaf(acc2[n][r], svs[y + 1][x + 1], s);
                    } else {
                        outd[e] = acc2[n][r];     // pure store (vres), combine adds xattn
                    }
                }
            }
        }
    }
}

// ---------------------------------------------------------------------------
// Attention body (k-split x4, software-pipelined, XCD-swizzled; smem 10240 B)
// ---------------------------------------------------------------------------
__device__ void attn_body(char* smem, int abi,
                          const float* __restrict__ tq,
                          const unsigned short* __restrict__ Kp,
                          const unsigned short* __restrict__ Vp,
                          float* __restrict__ Op, float* __restrict__ lp)
{
    const int xcd = abi & 7;
    const int t = abi >> 3;             // 0..199
    const int gsel = (t >= 100) ? 1 : 0;
    const int r0 = t - gsel * 100;      // 0..99
    const int grpId = (gsel << 3) | xcd;
    const int b = grpId >> 3, h = grpId & 7;
    const int sp = r0 / 25;
    const int q0 = (r0 % 25) * 128;
    const int tid = threadIdx.x;
    const int wave = tid >> 6, lane = tid & 63;
    const int qd = lane >> 4, ln = lane & 15;
    const int i0 = (sp == 0) ? 0 : (12 * sp + 1);
    const int i1 = 12 * sp + 13;

    const float* qb = tq + (long)b * kCN + (long)h * kHD * kN;
    const unsigned short* KpB = Kp + (long)(b * 8 + h) * 196 * 512 + ln * 32 + qd * 8;
    const unsigned short* VpB = Vp + (long)(b * 8 + h) * 49 * 2048 + ln * 32 + qd * 8;

    unsigned short* PsW = (unsigned short*)smem + wave * (32 * 40);

    const float qscale = kAttScale * kLog2e;
    Frag qf[2];
#pragma unroll
    for (int qt = 0; qt < 2; ++qt) {
        int qg = q0 + wave * 32 + qt * 16 + ln;
        bool qv = qg < kN;
#pragma unroll
        for (int j = 0; j < 8; ++j) {
            int d = qd * 8 + j;
            float v = qv ? qb[(long)d * kN + qg] * qscale : 0.f;
            qf[qt].u[j] = f2b(v);
        }
    }

    float4v o[2][2];
#pragma unroll
    for (int qt = 0; qt < 2; ++qt)
#pragma unroll
        for (int dh = 0; dh < 2; ++dh) o[qt][dh] = (float4v){0.f, 0.f, 0.f, 0.f};
    float lsum[2] = {0.f, 0.f};

    unsigned W[4][2][2];
    Frag ka[4];
#pragma unroll
    for (int m = 0; m < 4; ++m)
        ka[m].u4 = *(const uint4*)(KpB + (long)(4 * i0 + m) * 512);

    auto computeW = [&]() {
#pragma unroll
        for (int m = 0; m < 4; ++m) {
            float4v s0 = __builtin_amdgcn_mfma_f32_16x16x32_bf16(
                ka[m].s, qf[0].s, (float4v){0.f, 0.f, 0.f, 0.f}, 0, 0, 0);
            float4v s1 = __builtin_amdgcn_mfma_f32_16x16x32_bf16(
                ka[m].s, qf[1].s, (float4v){0.f, 0.f, 0.f, 0.f}, 0, 0, 0);
            float a0 = __builtin_amdgcn_exp2f(s0[0]);
            float a1 = __builtin_amdgcn_exp2f(s0[1]);
            float a2 = __builtin_amdgcn_exp2f(s0[2]);
            float a3 = __builtin_amdgcn_exp2f(s0[3]);
            lsum[0] += (a0 + a1) + (a2 + a3);
            W[m][0][0] = pk_trunc(a0, a1);
            W[m][0][1] = pk_trunc(a2, a3);
            float b0 = __builtin_amdgcn_exp2f(s1[0]);
            float b1 = __builtin_amdgcn_exp2f(s1[1]);
            float b2 = __builtin_amdgcn_exp2f(s1[2]);
            float b3 = __builtin_amdgcn_exp2f(s1[3]);
            lsum[1] += (b0 + b1) + (b2 + b3);
            W[m][1][0] = pk_trunc(b0, b1);
            W[m][1][1] = pk_trunc(b2, b3);
        }
    };

    computeW();
    if (i0 + 1 < i1) {
#pragma unroll
        for (int m = 0; m < 4; ++m)
            ka[m].u4 = *(const uint4*)(KpB + (long)(4 * (i0 + 1) + m) * 512);
    }

    for (int i = i0; i < i1; ++i) {
        Frag va[2][2];
#pragma unroll
        for (int g = 0; g < 2; ++g)
#pragma unroll
            for (int dh = 0; dh < 2; ++dh)
                va[g][dh].u4 = *(const uint4*)(VpB + (long)i * 2048 + (g * 2 + dh) * 512);

#pragma unroll
        for (int m = 0; m < 4; ++m)
#pragma unroll
            for (int qt = 0; qt < 2; ++qt)
                *(uint2*)&PsW[(qt * 16 + ln) * 40 + m * 16 + qd * 4] =
                    make_uint2(W[m][qt][0], W[m][qt][1]);

        if (i + 1 < i1) {
            computeW();
            if (i + 2 < i1) {
#pragma unroll
                for (int m = 0; m < 4; ++m)
                    ka[m].u4 = *(const uint4*)(KpB + (long)(4 * (i + 2) + m) * 512);
            }
        }

#pragma unroll
        for (int g = 0; g < 2; ++g) {
            Frag pa[2];
#pragma unroll
            for (int qt = 0; qt < 2; ++qt)
                pa[qt].u4 = *(const uint4*)&PsW[(qt * 16 + ln) * 40 + g * 32 + qd * 8];
#pragma unroll
            for (int qt = 0; qt < 2; ++qt)
#pragma unroll
                for (int dh = 0; dh < 2; ++dh)
                    o[qt][dh] = __builtin_amdgcn_mfma_f32_16x16x32_bf16(
                        pa[qt].s, va[g][dh].s, o[qt][dh], 0, 0, 0);
        }
    }

    const long grp = (long)(sp * 16 + b * 8 + h);
#pragma unroll
    for (int qt = 0; qt < 2; ++qt) {
        lsum[qt] += __shfl_xor(lsum[qt], 16, 64);
        lsum[qt] += __shfl_xor(lsum[qt], 32, 64);
        if (qd == 0)
            lp[grp * 3200 + q0 + wave * 32 + qt * 16 + ln] = lsum[qt];
#pragma unroll
        for (int dh = 0; dh < 2; ++dh)
#pragma unroll
            for (int r = 0; r < 4; ++r) {
                int q = q0 + wave * 32 + qt * 16 + qd * 4 + r;
                Op[(grp * 3200 + q) * 32 + dh * 16 + ln] = o[qt][dh][r];
            }
    }
}

// ---------------------------------------------------------------------------
// Mega dispatch 3: inverse DFTs + attention, interleaved (2624 blocks).
// Period 328 = 128 inv + 200 attn (×8 periods).
// ---------------------------------------------------------------------------
__global__ __launch_bounds__(256, 4)
void inv_attn_kernel(const float* __restrict__ fQ, const float* __restrict__ fK,
                     const float* __restrict__ fV, const float* __restrict__ cw,
                     float* __restrict__ dst1, float* __restrict__ dst2,
                     const float* __restrict__ skvp, const float* __restrict__ dww,
                     const float* __restrict__ dwb, const unsigned short* __restrict__ tw,
                     const float* __restrict__ tq,
                     const unsigned short* __restrict__ Kp,
                     const unsigned short* __restrict__ Vp,
                     float* __restrict__ Op, float* __restrict__ lp)
{
    __shared__ __align__(16) char smem[27648];
    const int per = blockIdx.x / 328;
    const int off = blockIdx.x % 328;
    if (off < 128)
        dft_inv_body(smem, per * 128 + off, fQ, fK, fV, cw, dst1, dst2, skvp, dww, dwb, tw);
    else
        attn_body(smem, per * 200 + (off - 128), tq, Kp, Vp, Op, lp);
}

// ---------------------------------------------------------------------------
// Combine 4 k-split partials, normalize, transpose, ADD into xo (holds vres).
// ---------------------------------------------------------------------------
__global__ __launch_bounds__(256)
void attn_combine_kernel(const float* __restrict__ Op, const float* __restrict__ lp,
                         float* __restrict__ xo)
{
    const int qc = blockIdx.x, bh = blockIdx.y;
    const int b = bh >> 3, h = bh & 7;
    const int q0 = qc * 64;
    __shared__ float T[32][65];
    const int tid = threadIdx.x;

    for (int i = tid; i < 64 * 32; i += 256) {
        int ql = i >> 5, d = i & 31;
        float ov = 0.f, l = 0.f;
#pragma unroll
        for (int s = 0; s < 4; ++s) {
            long g = (long)(s * 16 + bh);
            ov += Op[(g * 3200 + q0 + ql) * 32 + d];
            l  += lp[g * 3200 + q0 + ql];
        }
        T[d][ql] = ov / l;
    }
    __syncthreads();
    for (int i = tid; i < 32 * 64; i += 256) {
        int d = i >> 6, ql = i & 63;
        xo[(long)b * kCN + (long)(h * kHD + d) * kN + q0 + ql] += T[d][ql];
    }
}

// ---------------------------------------------------------------------------
// Output projections (dual GEMM, different inputs) -> gcat
// ---------------------------------------------------------------------------
__global__ __launch_bounds__(256)
void gemm_fused(const float* __restrict__ W0, const float* __restrict__ W1,
                const float* __restrict__ X0, const float* __restrict__ X1,
                const float* __restrict__ b0, const float* __restrict__ b1,
                float* __restrict__ Y0, float* __restrict__ Y1,
                int oHalf, int CI, long xbs, long ybs, int oOffset)
{
    __shared__ __align__(16) char smem[15360];
    const int b  = blockIdx.z;
    const int sel = blockIdx.y >= oHalf;
    const int o0 = (sel ? blockIdx.y - oHalf : blockIdx.y) * 64;
    const int oY = o0 + (sel ? oOffset : 0);
    gemm_bias_body(smem, sel ? W1 : W0, (sel ? X1 : X0) + (long)b * xbs,
                   sel ? b1 : b0, (sel ? Y1 : Y0) + (long)b * ybs,
                   o0, oY, blockIdx.x * 128, CI);
}

// ---------------------------------------------------------------------------
// BN+ReLU GEMM for the gate hidden layer (CI=512)
// ---------------------------------------------------------------------------
__global__ __launch_bounds__(256)
void gemm_bn_kernel(const float* __restrict__ Wm, const float* __restrict__ X,
                    const float* __restrict__ gamma, const float* __restrict__ beta,
                    float* __restrict__ Y, int CI, long xbs, long ybs)
{
    const int b  = blockIdx.z;
    const int o0 = blockIdx.y * 64;
    const int n0 = blockIdx.x * 128;
    const float* Xb = X + (long)b * xbs;
    float* Yb = Y + (long)b * ybs;

    __shared__ __align__(16) unsigned short Wt[64][40];
    __shared__ __align__(16) unsigned short Xt[128][40];

    const int tid = threadIdx.x;
    const int wave = tid >> 6, lane = tid & 63;
    const int ln = lane & 15, qd = lane >> 4;
    const int wy = wave >> 1, wx = wave & 1;

    const int ow = tid >> 2, kcw = tid & 3;
    const int nx = tid & 127, kcx = tid >> 7;
    const bool xvalid = (n0 + nx) < kN;

    float4v acc[2][4];
#pragma unroll
    for (int i = 0; i < 2; ++i)
#pragma unroll
        for (int j = 0; j < 4; ++j) acc[i][j] = (float4v){0.f, 0.f, 0.f, 0.f};

    float wpre[8], xpre[16];
    {
        const float* ws = Wm + (long)(o0 + ow) * CI + kcw * 8;
        *(float4*)&wpre[0] = *(const float4*)ws;
        *(float4*)&wpre[4] = *(const float4*)(ws + 4);
#pragma unroll
        for (int j = 0; j < 16; ++j)
            xpre[j] = xvalid ? Xb[(long)(kcx * 16 + j) * kN + n0 + nx] : 0.f;
    }

    for (int k0 = 0; k0 < CI; k0 += 32) {
        *(uint4*)&Wt[ow][kcw * 8]      = pk8(wpre);
        *(uint4*)&Xt[nx][kcx * 16]     = pk8(xpre);
        *(uint4*)&Xt[nx][kcx * 16 + 8] = pk8(xpre + 8);
        __syncthreads();

        if (k0 + 32 < CI) {
            const float* ws = Wm + (long)(o0 + ow) * CI + k0 + 32 + kcw * 8;
            *(float4*)&wpre[0] = *(const float4*)ws;
            *(float4*)&wpre[4] = *(const float4*)(ws + 4);
#pragma unroll
            for (int j = 0; j < 16; ++j)
                xpre[j] = xvalid ? Xb[(long)(k0 + 32 + kcx * 16 + j) * kN + n0 + nx] : 0.f;
        }

        Frag af[2], bf4[4];
#pragma unroll
        for (int mt = 0; mt < 2; ++mt)
            af[mt].u4 = *(const uint4*)&Wt[wy * 32 + mt * 16 + ln][qd * 8];
#pragma unroll
        for (int nt = 0; nt < 4; ++nt)
            bf4[nt].u4 = *(const uint4*)&Xt[wx * 64 + nt * 16 + ln][qd * 8];
#pragma unroll
        for (int mt = 0; mt < 2; ++mt)
#pragma unroll
            for (int nt = 0; nt < 4; ++nt)
                acc[mt][nt] = __builtin_amdgcn_mfma_f32_16x16x32_bf16(
                    af[mt].s, bf4[nt].s, acc[mt][nt], 0, 0, 0);
        __syncthreads();
    }

    const float rs = rsqrtf(1.0f + 1e-5f);
#pragma unroll
    for (int mt = 0; mt < 2; ++mt) {
        const int ob = o0 + wy * 32 + mt * 16 + qd * 4;
#pragma unroll
        for (int nt = 0; nt < 4; ++nt) {
            const int n = n0 + wx * 64 + nt * 16 + ln;
            if (n < kN) {
#pragma unroll
                for (int r = 0; r < 4; ++r) {
                    const int o = ob + r;
                    float v = fmaxf(fmaf(acc[mt][nt][r], gamma[o] * rs, beta[o]), 0.f);
                    Yb[(long)o * kN + n] = v;
                }
            }
        }
    }
}

// ---------------------------------------------------------------------------
// Fused gate + blend.
// ---------------------------------------------------------------------------
__global__ __launch_bounds__(256)
void gateblend_kernel(const float* __restrict__ hbuf, const float* __restrict__ w2,
                      const float* __restrict__ b2, const float* __restrict__ gcat,
                      float* __restrict__ out)
{
    const int n0 = blockIdx.x * 64;
    const int b = blockIdx.y;
    const int lane = threadIdx.x & 63;
    const int g = threadIdx.x >> 6;
    const float* hb = hbuf + (long)b * kCN + n0 + lane;
    float s = 0.f;
#pragma unroll 8
    for (int c = g * 64; c < g * 64 + 64; ++c)
        s = fmaf(w2[c], hb[(long)c * kN], s);
    __shared__ float red[4][64];
    __shared__ float sgate[64];
    red[g][lane] = s;
    __syncthreads();
    if (g == 0) {
        float t = red[0][lane] + red[1][lane] + red[2][lane] + red[3][lane];
        sgate[lane] = 1.f / (1.f + __expf(-(t + b2[0])));
    }
    __syncthreads();
    const float gt = sgate[lane];
    const float* osp = gcat + (long)b * 2 * kCN + n0 + lane;
    const float* otp = osp + kCN;
    float* op = out + (long)b * kCN + n0 + lane;
    for (int c = g; c < kC; c += 4) {
        float os = osp[(long)c * kN];
        float ot = otp[(long)c * kN];
        op[(long)c * kN] = gt * os + (1.f - gt) * ot;
    }
}

// ---------------------------------------------------------------------------
extern "C" void kernel_launch(void* const* d_in, const int* in_sizes, int n_in,
                              void* d_out, int out_size, void* d_ws, size_t ws_size,
                              hipStream_t stream)
{
    const float* x      = (const float*)d_in[0];
    const float* ctx    = (const float*)d_in[1];
    const float* s_q_w  = (const float*)d_in[2];
    const float* s_kv_w = (const float*)d_in[3];
    const float* s_p_w  = (const float*)d_in[4];
    const float* s_p_b  = (const float*)d_in[5];
    const float* s_dw_w = (const float*)d_in[6];
    const float* s_dw_b = (const float*)d_in[7];
    const float* t_q_w  = (const float*)d_in[8];
    const float* t_kv_w = (const float*)d_in[9];
    const float* t_p_w  = (const float*)d_in[10];
    const float* t_p_b  = (const float*)d_in[11];
    const float* t_cw   = (const float*)d_in[12];
    const float* g_w1   = (const float*)d_in[13];
    const float* g_bn_g = (const float*)d_in[14];
    const float* g_bn_b = (const float*)d_in[15];
    const float* g_w2   = (const float*)d_in[16];
    const float* g_b2   = (const float*)d_in[17];
    float* out = (float*)d_out;

    float* ws = (float*)d_ws;
    const long SPEC2 = (long)kB * kC * kSpec * 2;
    float* sq   = ws;                    // B*C*N   (sq -> vres -> tpre)
    float* skv  = sq   + kB * kCN;       // B*2C*N
    float* tq   = skv  + kB * 2 * kCN;   // B*C*N
    float* tkv  = tq   + kB * kCN;       // B*2C*N  (later: h)
    float* vloc = tkv  + kB * 2 * kCN;   // B*C*N   (spre result)
    float* fQ   = vloc + kB * kCN;
    float* fK   = fQ   + SPEC2;
    float* fV   = fK   + SPEC2;
    float* gcat = fV   + SPEC2;          // B*2C*N : [os ; ot]
    float* gate = gcat + kB * 2 * kCN;   // B*N (unused slot, kept for layout)
    unsigned short* tw = (unsigned short*)(gate + kB * kN);  // twiddles
    unsigned short* Kp = tw + TWTOT;                         // 16*196*512 u16
    unsigned short* Vp = Kp + (long)16 * 196 * 512;          // 16*49*2048 u16
    float* Opart = (float*)(Vp + (long)16 * 49 * 2048);      // 64*3200*32 f32
    float* lpart = Opart + (long)64 * 3200 * 32;             // 64*3200 f32

    dim3 blk(256, 1, 1);

    // 1: twiddle + all 4 projection GEMMs
    init_proj_kernel<<<dim3(1296), blk, 0, stream>>>(
        tw, x, ctx, s_q_w, t_q_w, s_kv_w, t_kv_w, sq, tq, skv, tkv);

    // 2: three forward DFTs + attention K/V prepack (interleaved period 290)
    fwd3_prepack_kernel<<<dim3(2320), blk, 0, stream>>>(
        sq, skv, tkv + kCN, fQ, fK, fV, tw, tkv, Kp, Vp);

    // 3: both inverse DFTs + attention (independent; interleaved co-schedule)
    inv_attn_kernel<<<dim3(2624), blk, 0, stream>>>(
        fQ, fK, fV, t_cw, vloc, sq, skv, s_dw_w, s_dw_b, tw,
        tq, Kp, Vp, Opart, lpart);

    // 4: combine k-split partials -> sq += xattn (sq holds vres)
    attn_combine_kernel<<<dim3(49, 16), blk, 0, stream>>>(Opart, lpart, sq);

    // 5: both output projections -> gcat
    gemm_fused<<<dim3(25, 8, kB), blk, 0, stream>>>(
        s_p_w, t_p_w, vloc, sq, s_p_b, t_p_b, gcat, gcat, 4, kC, kCN, 2 * kCN, 256);

    // 6: gate hidden GEMM (BN+ReLU)
    gemm_bn_kernel<<<dim3(25, 4, kB), blk, 0, stream>>>(g_w1, gcat, g_bn_g, g_bn_b, tkv, 2 * kC, 2 * kCN, kCN);

    // 7: gate + blend
    gateblend_kernel<<<dim3(49, kB), blk, 0, stream>>>(tkv, g_w2, g_b2, gcat, out);
}